// Round 4
// baseline (140.839 us; speedup 1.0000x reference)
//
#include <hip/hip_runtime.h>
#include <cstdint>
#include <cstddef>

namespace {

constexpr int kB = 16;
constexpr int kH = 512;
constexpr int kW = 512;
constexpr int kHW = kH * kW;
constexpr int kNS = 37632;     // NUM_POINTS * OVERSAMPLE
constexpr int kNUNC = 9408;    // 0.75 * NUM_POINTS
constexpr int kNRAND = 3136;
constexpr int kNPTS = 12544;
constexpr int kBins = 16384;   // 14-bit bins: exp(8) + mantissa(6)
constexpr int kRGB = 64;       // region blocks per batch
constexpr int kBXB = 16;       // bbox partial blocks per batch
constexpr int kRPB = 4;        // rand-point blocks per batch
constexpr int kSampleBlocks = (kB * kNS) / 512;          // 1176 (2 pts/thread)
constexpr int kBboxBlocks = kB * kBXB;                   // 256
constexpr int kRandBlocks = kB * kRPB;                   // 64

// workspace layout (bytes)
constexpr size_t OFF_PL  = 0;                                    // [B][NS] f32
constexpr size_t OFF_BBP = OFF_PL + (size_t)kB * kNS * 4;        // [B][16][4] i32
constexpr size_t OFF_OSP = OFF_BBP + (size_t)kB * kBXB * 4 * 4;  // [B][4] f32 os-point sums
constexpr size_t OFF_PLP = OFF_OSP + (size_t)kB * 4 * 4;         // [B][4][4] f32 rand partials
constexpr size_t OFF_RGP = OFF_PLP + (size_t)kB * kRPB * 4 * 4;  // [B][64][5] f32 region partials

__device__ __forceinline__ int SW(int bin) {  // bijection: conflict-free 16-bin row sums
  return ((bin & 15) << 10) | (bin >> 4);
}

} // namespace

__device__ __forceinline__ float sample_bilinear(const float* __restrict__ img,
                                                 float cx, float cy) {
  float x = cx * (float)kW - 0.5f;
  float y = cy * (float)kH - 0.5f;
  float x0f = floorf(x), y0f = floorf(y);
  float wx1 = x - x0f, wx0 = 1.0f - wx1;
  float wy1 = y - y0f, wy0 = 1.0f - wy1;
  int x0 = (int)x0f, y0 = (int)y0f;
  int x1 = x0 + 1, y1 = y0 + 1;
  int xc0 = min(max(x0, 0), kW - 1), xc1 = min(max(x1, 0), kW - 1);
  int yc0 = min(max(y0, 0), kH - 1), yc1 = min(max(y1, 0), kH - 1);
  float v00 = ((x0 >= 0) && (x0 < kW) && (y0 >= 0) && (y0 < kH)) ? img[yc0 * kW + xc0] : 0.0f;
  float v01 = ((x1 >= 0) && (x1 < kW) && (y0 >= 0) && (y0 < kH)) ? img[yc0 * kW + xc1] : 0.0f;
  float v10 = ((x0 >= 0) && (x0 < kW) && (y1 >= 0) && (y1 < kH)) ? img[yc1 * kW + xc0] : 0.0f;
  float v11 = ((x1 >= 0) && (x1 < kW) && (y1 >= 0) && (y1 < kH)) ? img[yc1 * kW + xc1] : 0.0f;
  return v00 * (wy0 * wx0) + v01 * (wy0 * wx1) + v10 * (wy1 * wx0) + v11 * (wy1 * wx1);
}

__device__ __forceinline__ void ce_terms(float z, float tt, float& ce_s, float& p_s,
                                         float& t_s, float& pt_s) {
  float a = expf(-fabsf(z));
  float ce = fmaxf(z, 0.0f) - z * tt + log1pf(a);
  float inv = 1.0f / (1.0f + a);
  float p = (z >= 0.0f) ? inv : a * inv;
  ce_s += ce; p_s += p; t_s += tt; pt_s += p * tt;
}

// ---- K1: sample pl (2 pts/thread) | bbox partials | rand-point CE partials ----
__global__ __launch_bounds__(256) void fused1_kernel(const float* __restrict__ pred,
                                                     const float* __restrict__ gt,
                                                     const float* __restrict__ coords_os,
                                                     const float* __restrict__ coords_rand,
                                                     float* __restrict__ pl,
                                                     int* __restrict__ bbp,
                                                     float* __restrict__ plp) {
  int blk = blockIdx.x;
  int t = threadIdx.x;

  if (blk < kSampleBlocks) {
    int idx = blk * 256 + t;                 // pair index; pairs never straddle batches
    float4 c2 = ((const float4*)coords_os)[idx];
    int b = (idx * 2) / kNS;
    const float* pred_b = pred + (size_t)b * kHW;
    float2 r;
    r.x = sample_bilinear(pred_b, c2.x, c2.y);
    r.y = sample_bilinear(pred_b, c2.z, c2.w);
    ((float2*)pl)[idx] = r;
    return;
  }

  if (blk < kSampleBlocks + kBboxBlocks) {
    __shared__ int r0[256], r1[256], r2[256], r3[256];
    int bb = blk - kSampleBlocks;
    int b = bb / kBXB;
    int c = bb % kBXB;
    constexpr int CHUNK4 = kHW / kBXB / 4;  // 4096 float4
    const float4* pred4 = (const float4*)(pred + (size_t)b * kHW) + (size_t)c * CHUNK4;
    int pbase = c * CHUNK4 * 4;
    int xmn = kW, xmx = -1, ymn = kH, ymx = -1;
    for (int i = t; i < CHUNK4; i += 256) {
      float4 z = pred4[i];
      int p = pbase + i * 4;
      int y = p >> 9;
      int x0 = p & (kW - 1);
      if (z.x > 0.0f) { xmn = min(xmn, x0);     xmx = max(xmx, x0);     ymn = min(ymn, y); ymx = max(ymx, y); }
      if (z.y > 0.0f) { xmn = min(xmn, x0 + 1); xmx = max(xmx, x0 + 1); ymn = min(ymn, y); ymx = max(ymx, y); }
      if (z.z > 0.0f) { xmn = min(xmn, x0 + 2); xmx = max(xmx, x0 + 2); ymn = min(ymn, y); ymx = max(ymx, y); }
      if (z.w > 0.0f) { xmn = min(xmn, x0 + 3); xmx = max(xmx, x0 + 3); ymn = min(ymn, y); ymx = max(ymx, y); }
    }
    r0[t] = xmn; r1[t] = xmx; r2[t] = ymn; r3[t] = ymx;
    __syncthreads();
    for (int s = 128; s > 0; s >>= 1) {
      if (t < s) {
        r0[t] = min(r0[t], r0[t + s]);
        r1[t] = max(r1[t], r1[t + s]);
        r2[t] = min(r2[t], r2[t + s]);
        r3[t] = max(r3[t], r3[t + s]);
      }
      __syncthreads();
    }
    if (t == 0) {
      int* o = bbp + ((size_t)b * kBXB + c) * 4;
      o[0] = r0[0]; o[1] = r1[0]; o[2] = r2[0]; o[3] = r3[0];
    }
    return;
  }

  // rand-point CE partials (independent of selection)
  {
    __shared__ float red[4][256];
    int q = blk - kSampleBlocks - kBboxBlocks;
    int b = q / kRPB;
    int c = q % kRPB;
    const float* pred_b = pred + (size_t)b * kHW;
    const float* gt_b = gt + (size_t)b * kHW;
    float ce_s = 0.0f, p_s = 0.0f, t_s = 0.0f, pt_s = 0.0f;
    for (int e = c * 256 + t; e < kNRAND; e += kRPB * 256) {
      float2 cc = *(const float2*)&coords_rand[((size_t)b * kNRAND + e) * 2];
      float z = sample_bilinear(pred_b, cc.x, cc.y);
      float tt = sample_bilinear(gt_b, cc.x, cc.y);
      ce_terms(z, tt, ce_s, p_s, t_s, pt_s);
    }
    red[0][t] = ce_s; red[1][t] = p_s; red[2][t] = t_s; red[3][t] = pt_s;
    __syncthreads();
    for (int s = 128; s > 0; s >>= 1) {
      if (t < s) {
        red[0][t] += red[0][t + s];
        red[1][t] += red[1][t + s];
        red[2][t] += red[2][t + s];
        red[3][t] += red[3][t + s];
      }
      __syncthreads();
    }
    if (t == 0) {
      float* o = plp + ((size_t)b * kRPB + c) * 4;
      o[0] = red[0][0]; o[1] = red[1][0]; o[2] = red[2][0]; o[3] = red[3][0];
    }
  }
}

// ---- K2: per-batch select (14-bit swizzled hist) + os-point CE, fused ----
__global__ __launch_bounds__(1024) void select_ce_kernel(const float* __restrict__ pl,
                                                         const float* __restrict__ gt,
                                                         const float* __restrict__ coords_os,
                                                         float* __restrict__ osp) {
  constexpr int C = 37;            // ceil(37632/1024)
  constexpr int CAP = 1024;
  int b = blockIdx.x;
  int t = threadIdx.x;
  const float* pl_b = pl + (size_t)b * kNS;
  const float* gt_b = gt + (size_t)b * kHW;
  const float* co_b = coords_os + (size_t)b * kNS * 2;

  __shared__ unsigned hist[kBins];     // 64 KB; reused as reduction space later
  __shared__ unsigned scan[1024];      // reused as candidate list
  __shared__ int s_bstar, s_need, s_ccnt, s_round;

  for (int i = t; i < kBins; i += 1024) hist[i] = 0u;
  if (t == 0) s_ccnt = 0;
  __syncthreads();

  // pass 1: histogram (coalesced loads, swizzled bins)
  unsigned ub[C];
#pragma unroll
  for (int j = 0; j < C; ++j) {
    int idx = j * 1024 + t;
    if (idx < kNS) {
      unsigned u = __float_as_uint(pl_b[idx]) & 0x7fffffffu;
      ub[j] = u;
      atomicAdd(&hist[SW((int)(u >> 17))], 1u);
    } else {
      ub[j] = 0xffffffffu;
    }
  }
  __syncthreads();

  // 16-bin sums (conflict-free: lane-stride-1) + Hillis scan over 1024
  unsigned s = 0;
#pragma unroll
  for (int k = 0; k < 16; ++k) s += hist[(k << 10) | t];
  scan[t] = s;
  __syncthreads();
  for (int off = 1; off < 1024; off <<= 1) {
    unsigned v = (t >= off) ? scan[t - off] : 0u;
    __syncthreads();
    scan[t] += v;
    __syncthreads();
  }
  unsigned incl = scan[t];
  unsigned excl = incl - s;
  const unsigned K = (unsigned)kNUNC;
  if (excl < K && incl >= K) {       // exactly one thread
    unsigned cum = excl;
    int bs = t * 16 + 15;
    for (int k = 0; k < 16; ++k) {
      unsigned h = hist[(k << 10) | t];
      if (cum + h >= K) { bs = t * 16 + k; break; }
      cum += h;
    }
    s_bstar = bs;
    s_need = (int)(K - cum);
  }
  __syncthreads();
  int bstar = s_bstar;
  int need = s_need;

  // pass 2: below-boundary -> CE directly; boundary bin -> candidate list
  float ce_s = 0.0f, p_s = 0.0f, t_s = 0.0f, pt_s = 0.0f;
  int* cand = (int*)scan;
#pragma unroll
  for (int j = 0; j < C; ++j) {
    int idx = j * 1024 + t;
    if (idx < kNS) {
      int bin = (int)(ub[j] >> 17);
      if (bin < bstar) {
        float z = pl_b[idx];
        float2 cc = *(const float2*)&co_b[(size_t)idx * 2];
        float tt = sample_bilinear(gt_b, cc.x, cc.y);
        ce_terms(z, tt, ce_s, p_s, t_s, pt_s);
      } else if (bin == bstar) {
        int pos = atomicAdd(&s_ccnt, 1);
        if (pos < CAP) cand[pos] = idx;
      }
    }
  }
  __syncthreads();
  int c = s_ccnt;

  if (c <= CAP) {
    for (int i = t; i < c; i += 1024) {
      int my = cand[i];
      int r = 0;
      for (int k = 0; k < c; ++k) r += (cand[k] < my) ? 1 : 0;
      if (r < need) {
        float z = pl_b[my];
        float2 cc = *(const float2*)&co_b[(size_t)my * 2];
        float tt = sample_bilinear(gt_b, cc.x, cc.y);
        ce_terms(z, tt, ce_s, p_s, t_s, pt_s);
      }
    }
    __syncthreads();
  } else {
    // deterministic ordered-scan fallback (duplicate-heavy pathological data)
    if (t == 0) s_round = 0;
    __syncthreads();
    for (int j = 0; j < C; ++j) {
      int idx = j * 1024 + t;
      unsigned flag = (idx < kNS && (int)(ub[j] >> 17) == bstar) ? 1u : 0u;
      scan[t] = flag;
      __syncthreads();
      for (int off = 1; off < 1024; off <<= 1) {
        unsigned v = (t >= off) ? scan[t - off] : 0u;
        __syncthreads();
        scan[t] += v;
        __syncthreads();
      }
      int base = s_round;
      if (flag && base + (int)(scan[t] - flag) < need) {
        float z = pl_b[idx];
        float2 cc = *(const float2*)&co_b[(size_t)idx * 2];
        float tt = sample_bilinear(gt_b, cc.x, cc.y);
        ce_terms(z, tt, ce_s, p_s, t_s, pt_s);
      }
      __syncthreads();
      if (t == 0) s_round = base + (int)scan[1023];
      __syncthreads();
    }
  }

  // block reduction (reuse hist as float[4][1024])
  float* red = (float*)hist;
  red[0 * 1024 + t] = ce_s; red[1 * 1024 + t] = p_s;
  red[2 * 1024 + t] = t_s;  red[3 * 1024 + t] = pt_s;
  __syncthreads();
  for (int st = 512; st > 0; st >>= 1) {
    if (t < st) {
#pragma unroll
      for (int q = 0; q < 4; ++q) red[q * 1024 + t] += red[q * 1024 + t + st];
    }
    __syncthreads();
  }
  if (t == 0) {
    float* o = osp + (size_t)b * 4;
    o[0] = red[0]; o[1] = red[1 * 1024]; o[2] = red[2 * 1024]; o[3] = red[3 * 1024];
  }
}

// ---- K3: region BCE + dice partial sums; bbox derived inline from partials ----
__global__ __launch_bounds__(256) void region_kernel(const float* __restrict__ pred,
                                                     const float* __restrict__ gt,
                                                     const int* __restrict__ bbp,
                                                     float* __restrict__ rgp) {
  constexpr int CHUNK4 = kHW / kRGB / 4;  // 1024 float4 per block
  int b = blockIdx.x / kRGB;
  int c = blockIdx.x % kRGB;
  int t = threadIdx.x;
  const float4* pred4 = (const float4*)(pred + (size_t)b * kHW) + (size_t)c * CHUNK4;
  const float4* gt4 = (const float4*)(gt + (size_t)b * kHW) + (size_t)c * CHUNK4;

  int xmn = kW, xmx = -1, ymn = kH, ymx = -1;
#pragma unroll
  for (int q = 0; q < kBXB; ++q) {
    const int4 pb = *(const int4*)(bbp + ((size_t)b * kBXB + q) * 4);
    xmn = min(xmn, pb.x); xmx = max(xmx, pb.y);
    ymn = min(ymn, pb.z); ymx = max(ymx, pb.w);
  }
  bool empty = (xmx < 0);
  int x1 = empty ? 0 : xmn;
  int x2 = min(empty ? (kW - 1) : xmx, kW - 1);
  int y1 = empty ? 0 : ymn;
  int y2 = min(empty ? (kH - 1) : ymx, kH - 1);
  bool valid = (x2 > x1) && (y2 > y1);

  int pbase = c * CHUNK4 * 4;
  float wsum = 0.0f, bcew = 0.0f, inter = 0.0f, pw = 0.0f, gw = 0.0f;
  for (int i = t; i < CHUNK4; i += 256) {
    float4 zv = pred4[i];
    float4 gv = gt4[i];
    int p = pbase + i * 4;
    int y = p >> 9;
    int x0 = p & (kW - 1);
    bool iny = valid && (y >= y1) && (y <= y2);
#pragma unroll
    for (int l = 0; l < 4; ++l) {
      float z = (l == 0) ? zv.x : (l == 1) ? zv.y : (l == 2) ? zv.z : zv.w;
      float g = (l == 0) ? gv.x : (l == 1) ? gv.y : (l == 2) ? gv.z : gv.w;
      int x = x0 + l;
      float w = (iny && x >= x1 && x <= x2) ? 2.0f : 0.5f;
      float a = expf(-fabsf(z));
      float sp = fmaxf(-z, 0.0f) + log1pf(a);   // softplus(-z) = -log_sigmoid(z)
      float bce = sp + (1.0f - g) * z;
      float inv = 1.0f / (1.0f + a);
      float pp = (z >= 0.0f) ? inv : a * inv;
      wsum += w;
      bcew += bce * w;
      inter += pp * g * w;
      pw += pp * w;
      gw += g * w;
    }
  }
  __shared__ float red[5][256];
  red[0][t] = wsum; red[1][t] = bcew; red[2][t] = inter; red[3][t] = pw; red[4][t] = gw;
  __syncthreads();
  for (int s = 128; s > 0; s >>= 1) {
    if (t < s) {
#pragma unroll
      for (int q = 0; q < 5; ++q) red[q][t] += red[q][t + s];
    }
    __syncthreads();
  }
  if (t == 0) {
    float* o = rgp + ((size_t)b * kRGB + c) * 5;
    o[0] = red[0][0]; o[1] = red[1][0]; o[2] = red[2][0]; o[3] = red[3][0]; o[4] = red[4][0];
  }
}

// ---- K4: finalize in f64 ----
__global__ __launch_bounds__(64) void finalize_kernel(const float* __restrict__ osp,
                                                      const float* __restrict__ plp,
                                                      const float* __restrict__ rgp,
                                                      float* __restrict__ out) {
  __shared__ double sh[kB][4];
  int t = threadIdx.x;
  if (t < kB) {
    const float* o = osp + (size_t)t * 4;
    double ce = o[0], p = o[1], tt = o[2], pt = o[3];
    for (int c = 0; c < kRPB; ++c) {
      const float* q = plp + ((size_t)t * kRPB + c) * 4;
      ce += q[0]; p += q[1]; tt += q[2]; pt += q[3];
    }
    double ws = 0, bc = 0, in = 0, pw = 0, gw = 0;
    for (int c = 0; c < kRGB; ++c) {
      const float* q = rgp + ((size_t)t * kRGB + c) * 5;
      ws += q[0]; bc += q[1]; in += q[2]; pw += q[3]; gw += q[4];
    }
    sh[t][0] = ce / (double)kNPTS;
    sh[t][1] = 1.0 - (2.0 * pt + 1.0) / (p + tt + 1.0);
    double wss = ws > 1e-6 ? ws : 1e-6;
    sh[t][2] = bc / wss;
    sh[t][3] = 1.0 - (2.0 * in + 1.0) / (pw + gw + 1.0);
  }
  __syncthreads();
  if (t == 0) {
    double a = 0, b = 0, c = 0, d = 0;
    for (int i = 0; i < kB; ++i) { a += sh[i][0]; b += sh[i][1]; c += sh[i][2]; d += sh[i][3]; }
    out[0] = (float)(a / 16.0);
    out[1] = (float)(b / 16.0);
    out[2] = (float)(c / 16.0);
    out[3] = (float)(d / 16.0);
  }
}

extern "C" void kernel_launch(void* const* d_in, const int* in_sizes, int n_in,
                              void* d_out, int out_size, void* d_ws, size_t ws_size,
                              hipStream_t stream) {
  const float* pred = (const float*)d_in[0];
  const float* gt = (const float*)d_in[1];
  const float* coords_os = (const float*)d_in[2];
  const float* coords_rand = (const float*)d_in[3];
  float* out = (float*)d_out;
  char* ws = (char*)d_ws;

  float* pl = (float*)(ws + OFF_PL);
  int* bbp = (int*)(ws + OFF_BBP);
  float* osp = (float*)(ws + OFF_OSP);
  float* plp = (float*)(ws + OFF_PLP);
  float* rgp = (float*)(ws + OFF_RGP);

  fused1_kernel<<<kSampleBlocks + kBboxBlocks + kRandBlocks, 256, 0, stream>>>(
      pred, gt, coords_os, coords_rand, pl, bbp, plp);
  select_ce_kernel<<<kB, 1024, 0, stream>>>(pl, gt, coords_os, osp);
  region_kernel<<<kB * kRGB, 256, 0, stream>>>(pred, gt, bbp, rgp);
  finalize_kernel<<<1, 64, 0, stream>>>(osp, plp, rgp, out);
}

// Round 5
// 80.820 us; speedup vs baseline: 1.7426x; 1.7426x over previous
//
#include <hip/hip_runtime.h>
#include <cstdint>
#include <cstddef>

namespace {

constexpr int kB = 16;
constexpr int kH = 512;
constexpr int kW = 512;
constexpr int kHW = kH * kW;
constexpr int kNS = 37632;     // NUM_POINTS * OVERSAMPLE
constexpr int kNUNC = 9408;    // 0.75 * NUM_POINTS
constexpr int kNRAND = 3136;
constexpr int kNPTS = 12544;
constexpr int kBins = 16384;   // 14-bit bins: exp(8) + mantissa(6)
constexpr int kRGB = 64;       // region blocks per batch
constexpr int kBXB = 16;       // bbox partial blocks per batch
constexpr int kRPB = 4;        // rand-point blocks per batch
constexpr int kPLB = 32;       // os-pointloss blocks per batch
constexpr int kSampleBlocks = (kB * kNS) / 512;          // 1176 (2 pts/thread)
constexpr int kBboxBlocks = kB * kBXB;                   // 256
constexpr int kRandBlocks = kB * kRPB;                   // 64
constexpr int kHStride = 1025;                           // hist row stride (words)

// workspace layout (bytes)
constexpr size_t OFF_PL   = 0;                                    // [B][NS] f32
constexpr size_t OFF_SEL  = OFF_PL + (size_t)kB * kNS * 4;        // [B][NS] u8
constexpr size_t OFF_BBP  = OFF_SEL + (size_t)kB * kNS;           // [B][16][4] i32
constexpr size_t OFF_PLP  = OFF_BBP + (size_t)kB * kBXB * 4 * 4;  // [B][4][4] f32 rand partials
constexpr size_t OFF_PLP2 = OFF_PLP + (size_t)kB * kRPB * 4 * 4;  // [B][32][4] f32 os partials
constexpr size_t OFF_RGP  = OFF_PLP2 + (size_t)kB * kPLB * 4 * 4; // [B][64][5] f32 region partials

__device__ __forceinline__ int SW(int bin) {
  // reads hist[k*1025 + t] lane-stride-1 (conflict-free); adjacent bins -> distinct banks
  return (bin & 15) * kHStride + (bin >> 4);
}

} // namespace

__device__ __forceinline__ float sample_bilinear(const float* __restrict__ img,
                                                 float cx, float cy) {
  float x = cx * (float)kW - 0.5f;
  float y = cy * (float)kH - 0.5f;
  float x0f = floorf(x), y0f = floorf(y);
  float wx1 = x - x0f, wx0 = 1.0f - wx1;
  float wy1 = y - y0f, wy0 = 1.0f - wy1;
  int x0 = (int)x0f, y0 = (int)y0f;
  int x1 = x0 + 1, y1 = y0 + 1;
  int xc0 = min(max(x0, 0), kW - 1), xc1 = min(max(x1, 0), kW - 1);
  int yc0 = min(max(y0, 0), kH - 1), yc1 = min(max(y1, 0), kH - 1);
  float v00 = ((x0 >= 0) && (x0 < kW) && (y0 >= 0) && (y0 < kH)) ? img[yc0 * kW + xc0] : 0.0f;
  float v01 = ((x1 >= 0) && (x1 < kW) && (y0 >= 0) && (y0 < kH)) ? img[yc0 * kW + xc1] : 0.0f;
  float v10 = ((x0 >= 0) && (x0 < kW) && (y1 >= 0) && (y1 < kH)) ? img[yc1 * kW + xc0] : 0.0f;
  float v11 = ((x1 >= 0) && (x1 < kW) && (y1 >= 0) && (y1 < kH)) ? img[yc1 * kW + xc1] : 0.0f;
  return v00 * (wy0 * wx0) + v01 * (wy0 * wx1) + v10 * (wy1 * wx0) + v11 * (wy1 * wx1);
}

__device__ __forceinline__ void ce_terms(float z, float tt, float& ce_s, float& p_s,
                                         float& t_s, float& pt_s) {
  float a = expf(-fabsf(z));
  float ce = fmaxf(z, 0.0f) - z * tt + log1pf(a);
  float inv = 1.0f / (1.0f + a);
  float p = (z >= 0.0f) ? inv : a * inv;
  ce_s += ce; p_s += p; t_s += tt; pt_s += p * tt;
}

// ---- K1: sample pl (2 pts/thread) | bbox partials | rand-point CE partials ----
__global__ __launch_bounds__(256) void fused1_kernel(const float* __restrict__ pred,
                                                     const float* __restrict__ gt,
                                                     const float* __restrict__ coords_os,
                                                     const float* __restrict__ coords_rand,
                                                     float* __restrict__ pl,
                                                     int* __restrict__ bbp,
                                                     float* __restrict__ plp) {
  int blk = blockIdx.x;
  int t = threadIdx.x;

  if (blk < kSampleBlocks) {
    int idx = blk * 256 + t;                 // pair index; pairs never straddle batches
    float4 c2 = ((const float4*)coords_os)[idx];
    int b = (idx * 2) / kNS;
    const float* pred_b = pred + (size_t)b * kHW;
    float2 r;
    r.x = sample_bilinear(pred_b, c2.x, c2.y);
    r.y = sample_bilinear(pred_b, c2.z, c2.w);
    ((float2*)pl)[idx] = r;
    return;
  }

  if (blk < kSampleBlocks + kBboxBlocks) {
    __shared__ int r0[256], r1[256], r2[256], r3[256];
    int bb = blk - kSampleBlocks;
    int b = bb / kBXB;
    int c = bb % kBXB;
    constexpr int CHUNK4 = kHW / kBXB / 4;  // 4096 float4
    const float4* pred4 = (const float4*)(pred + (size_t)b * kHW) + (size_t)c * CHUNK4;
    int pbase = c * CHUNK4 * 4;
    int xmn = kW, xmx = -1, ymn = kH, ymx = -1;
    for (int i = t; i < CHUNK4; i += 256) {
      float4 z = pred4[i];
      int p = pbase + i * 4;
      int y = p >> 9;
      int x0 = p & (kW - 1);
      if (z.x > 0.0f) { xmn = min(xmn, x0);     xmx = max(xmx, x0);     ymn = min(ymn, y); ymx = max(ymx, y); }
      if (z.y > 0.0f) { xmn = min(xmn, x0 + 1); xmx = max(xmx, x0 + 1); ymn = min(ymn, y); ymx = max(ymx, y); }
      if (z.z > 0.0f) { xmn = min(xmn, x0 + 2); xmx = max(xmx, x0 + 2); ymn = min(ymn, y); ymx = max(ymx, y); }
      if (z.w > 0.0f) { xmn = min(xmn, x0 + 3); xmx = max(xmx, x0 + 3); ymn = min(ymn, y); ymx = max(ymx, y); }
    }
    r0[t] = xmn; r1[t] = xmx; r2[t] = ymn; r3[t] = ymx;
    __syncthreads();
    for (int s = 128; s > 0; s >>= 1) {
      if (t < s) {
        r0[t] = min(r0[t], r0[t + s]);
        r1[t] = max(r1[t], r1[t + s]);
        r2[t] = min(r2[t], r2[t + s]);
        r3[t] = max(r3[t], r3[t + s]);
      }
      __syncthreads();
    }
    if (t == 0) {
      int* o = bbp + ((size_t)b * kBXB + c) * 4;
      o[0] = r0[0]; o[1] = r1[0]; o[2] = r2[0]; o[3] = r3[0];
    }
    return;
  }

  // rand-point CE partials (independent of selection)
  {
    __shared__ float red[4][256];
    int q = blk - kSampleBlocks - kBboxBlocks;
    int b = q / kRPB;
    int c = q % kRPB;
    const float* pred_b = pred + (size_t)b * kHW;
    const float* gt_b = gt + (size_t)b * kHW;
    float ce_s = 0.0f, p_s = 0.0f, t_s = 0.0f, pt_s = 0.0f;
    for (int e = c * 256 + t; e < kNRAND; e += kRPB * 256) {
      float2 cc = *(const float2*)&coords_rand[((size_t)b * kNRAND + e) * 2];
      float z = sample_bilinear(pred_b, cc.x, cc.y);
      float tt = sample_bilinear(gt_b, cc.x, cc.y);
      ce_terms(z, tt, ce_s, p_s, t_s, pt_s);
    }
    red[0][t] = ce_s; red[1][t] = p_s; red[2][t] = t_s; red[3][t] = pt_s;
    __syncthreads();
    for (int s = 128; s > 0; s >>= 1) {
      if (t < s) {
        red[0][t] += red[0][t + s];
        red[1][t] += red[1][t + s];
        red[2][t] += red[2][t + s];
        red[3][t] += red[3][t + s];
      }
      __syncthreads();
    }
    if (t == 0) {
      float* o = plp + ((size_t)b * kRPB + c) * 4;
      o[0] = red[0][0]; o[1] = red[1][0]; o[2] = red[2][0]; o[3] = red[3][0];
    }
  }
}

// ---- K2: per-batch selection only (14-bit hist, conflict-free layout) ----
__global__ __launch_bounds__(1024) void select_kernel(const float* __restrict__ pl,
                                                      unsigned char* __restrict__ sel) {
  constexpr int C = 37;            // ceil(37632/1024)
  constexpr int CAP = 1024;
  int b = blockIdx.x;
  int t = threadIdx.x;
  const float* pl_b = pl + (size_t)b * kNS;
  unsigned char* sel_b = sel + (size_t)b * kNS;

  __shared__ unsigned hist[16 * kHStride];   // 65.6 KB swizzled
  __shared__ unsigned scan[1024];
  __shared__ int cand[CAP];
  __shared__ int s_bstar, s_need, s_ccnt, s_round;

  for (int i = t; i < 16 * kHStride; i += 1024) hist[i] = 0u;
  if (t == 0) s_ccnt = 0;
  __syncthreads();

  // pass 1: histogram (coalesced loads, swizzled bins)
  unsigned ub[C];
#pragma unroll
  for (int j = 0; j < C; ++j) {
    int idx = j * 1024 + t;
    if (idx < kNS) {
      unsigned u = __float_as_uint(pl_b[idx]) & 0x7fffffffu;
      ub[j] = u;
      atomicAdd(&hist[SW((int)(u >> 17))], 1u);
    } else {
      ub[j] = 0xffffffffu;
    }
  }
  __syncthreads();

  // 16-bin sums (lane-stride-1 reads) + Hillis scan over 1024
  unsigned s = 0;
#pragma unroll
  for (int k = 0; k < 16; ++k) s += hist[k * kHStride + t];
  scan[t] = s;
  __syncthreads();
  for (int off = 1; off < 1024; off <<= 1) {
    unsigned v = (t >= off) ? scan[t - off] : 0u;
    __syncthreads();
    scan[t] += v;
    __syncthreads();
  }
  unsigned incl = scan[t];
  unsigned excl = incl - s;
  const unsigned K = (unsigned)kNUNC;
  if (excl < K && incl >= K) {       // exactly one thread
    unsigned cum = excl;
    int bs = t * 16 + 15;
    for (int k = 0; k < 16; ++k) {
      unsigned h = hist[k * kHStride + t];
      if (cum + h >= K) { bs = t * 16 + k; break; }
      cum += h;
    }
    s_bstar = bs;
    s_need = (int)(K - cum);
  }
  __syncthreads();
  int bstar = s_bstar;
  int need = s_need;

  // pass 2: mark below-boundary; collect boundary-bin candidates
#pragma unroll
  for (int j = 0; j < C; ++j) {
    int idx = j * 1024 + t;
    if (idx < kNS) {
      int bin = (int)(ub[j] >> 17);
      unsigned char f = (bin < bstar) ? 1 : 0;
      if (bin == bstar) {
        int pos = atomicAdd(&s_ccnt, 1);
        if (pos < CAP) cand[pos] = idx;
      }
      sel_b[idx] = f;
    }
  }
  __syncthreads();
  int c = s_ccnt;

  if (c <= CAP) {
    for (int i = t; i < c; i += 1024) {
      int my = cand[i];
      int r = 0;
      for (int k = 0; k < c; ++k) r += (cand[k] < my) ? 1 : 0;
      if (r < need) sel_b[my] = 1;
    }
  } else {
    // deterministic ordered-scan fallback (duplicate-heavy pathological data)
    if (t == 0) s_round = 0;
    __syncthreads();
    for (int j = 0; j < C; ++j) {
      int idx = j * 1024 + t;
      unsigned flag = (idx < kNS && (int)(ub[j] >> 17) == bstar) ? 1u : 0u;
      scan[t] = flag;
      __syncthreads();
      for (int off = 1; off < 1024; off <<= 1) {
        unsigned v = (t >= off) ? scan[t - off] : 0u;
        __syncthreads();
        scan[t] += v;
        __syncthreads();
      }
      int base = s_round;
      if (flag && base + (int)(scan[t] - flag) < need) sel_b[idx] = 1;
      __syncthreads();
      if (t == 0) s_round = base + (int)scan[1023];
      __syncthreads();
    }
  }
}

// ---- K3: os-point CE (blocks < kB*kPLB) | region BCE+dice (rest) ----
__global__ __launch_bounds__(256) void fused3_kernel(const float* __restrict__ pred,
                                                     const float* __restrict__ gt,
                                                     const float* __restrict__ coords_os,
                                                     const float* __restrict__ pl,
                                                     const unsigned char* __restrict__ sel,
                                                     const int* __restrict__ bbp,
                                                     float* __restrict__ plp2,
                                                     float* __restrict__ rgp) {
  int blk = blockIdx.x;
  int t = threadIdx.x;

  if (blk < kB * kPLB) {
    __shared__ float red[4][256];
    int b = blk / kPLB;
    int c = blk % kPLB;
    const float* gt_b = gt + (size_t)b * kHW;
    float ce_s = 0.0f, p_s = 0.0f, t_s = 0.0f, pt_s = 0.0f;
    for (int e = c * 256 + t; e < kNS; e += kPLB * 256) {
      if (!sel[(size_t)b * kNS + e]) continue;
      float2 cc = *(const float2*)&coords_os[((size_t)b * kNS + e) * 2];
      float z = pl[(size_t)b * kNS + e];
      float tt = sample_bilinear(gt_b, cc.x, cc.y);
      ce_terms(z, tt, ce_s, p_s, t_s, pt_s);
    }
    red[0][t] = ce_s; red[1][t] = p_s; red[2][t] = t_s; red[3][t] = pt_s;
    __syncthreads();
    for (int s = 128; s > 0; s >>= 1) {
      if (t < s) {
        red[0][t] += red[0][t + s];
        red[1][t] += red[1][t + s];
        red[2][t] += red[2][t + s];
        red[3][t] += red[3][t + s];
      }
      __syncthreads();
    }
    if (t == 0) {
      float* o = plp2 + ((size_t)b * kPLB + c) * 4;
      o[0] = red[0][0]; o[1] = red[1][0]; o[2] = red[2][0]; o[3] = red[3][0];
    }
    return;
  }

  // region portion
  {
    constexpr int CHUNK4 = kHW / kRGB / 4;  // 1024 float4 per block
    int q = blk - kB * kPLB;
    int b = q / kRGB;
    int c = q % kRGB;
    const float4* pred4 = (const float4*)(pred + (size_t)b * kHW) + (size_t)c * CHUNK4;
    const float4* gt4 = (const float4*)(gt + (size_t)b * kHW) + (size_t)c * CHUNK4;

    int xmn = kW, xmx = -1, ymn = kH, ymx = -1;
#pragma unroll
    for (int u = 0; u < kBXB; ++u) {
      const int4 pb = *(const int4*)(bbp + ((size_t)b * kBXB + u) * 4);
      xmn = min(xmn, pb.x); xmx = max(xmx, pb.y);
      ymn = min(ymn, pb.z); ymx = max(ymx, pb.w);
    }
    bool empty = (xmx < 0);
    int x1 = empty ? 0 : xmn;
    int x2 = min(empty ? (kW - 1) : xmx, kW - 1);
    int y1 = empty ? 0 : ymn;
    int y2 = min(empty ? (kH - 1) : ymx, kH - 1);
    bool valid = (x2 > x1) && (y2 > y1);

    int pbase = c * CHUNK4 * 4;
    float wsum = 0.0f, bcew = 0.0f, inter = 0.0f, pw = 0.0f, gw = 0.0f;
    for (int i = t; i < CHUNK4; i += 256) {
      float4 zv = pred4[i];
      float4 gv = gt4[i];
      int p = pbase + i * 4;
      int y = p >> 9;
      int x0 = p & (kW - 1);
      bool iny = valid && (y >= y1) && (y <= y2);
#pragma unroll
      for (int l = 0; l < 4; ++l) {
        float z = (l == 0) ? zv.x : (l == 1) ? zv.y : (l == 2) ? zv.z : zv.w;
        float g = (l == 0) ? gv.x : (l == 1) ? gv.y : (l == 2) ? gv.z : gv.w;
        int x = x0 + l;
        float w = (iny && x >= x1 && x <= x2) ? 2.0f : 0.5f;
        float a = expf(-fabsf(z));
        float sp = fmaxf(-z, 0.0f) + log1pf(a);   // softplus(-z) = -log_sigmoid(z)
        float bce = sp + (1.0f - g) * z;
        float inv = 1.0f / (1.0f + a);
        float pp = (z >= 0.0f) ? inv : a * inv;
        wsum += w;
        bcew += bce * w;
        inter += pp * g * w;
        pw += pp * w;
        gw += g * w;
      }
    }
    __shared__ float red5[5][256];
    red5[0][t] = wsum; red5[1][t] = bcew; red5[2][t] = inter; red5[3][t] = pw; red5[4][t] = gw;
    __syncthreads();
    for (int s = 128; s > 0; s >>= 1) {
      if (t < s) {
#pragma unroll
        for (int u = 0; u < 5; ++u) red5[u][t] += red5[u][t + s];
      }
      __syncthreads();
    }
    if (t == 0) {
      float* o = rgp + ((size_t)b * kRGB + c) * 5;
      o[0] = red5[0][0]; o[1] = red5[1][0]; o[2] = red5[2][0]; o[3] = red5[3][0]; o[4] = red5[4][0];
    }
  }
}

// ---- K4: finalize in f64 ----
__global__ __launch_bounds__(64) void finalize_kernel(const float* __restrict__ plp,
                                                      const float* __restrict__ plp2,
                                                      const float* __restrict__ rgp,
                                                      float* __restrict__ out) {
  __shared__ double sh[kB][4];
  int t = threadIdx.x;
  if (t < kB) {
    double ce = 0, p = 0, tt = 0, pt = 0;
    for (int c = 0; c < kRPB; ++c) {
      const float* q = plp + ((size_t)t * kRPB + c) * 4;
      ce += q[0]; p += q[1]; tt += q[2]; pt += q[3];
    }
    for (int c = 0; c < kPLB; ++c) {
      const float* q = plp2 + ((size_t)t * kPLB + c) * 4;
      ce += q[0]; p += q[1]; tt += q[2]; pt += q[3];
    }
    double ws = 0, bc = 0, in = 0, pw = 0, gw = 0;
    for (int c = 0; c < kRGB; ++c) {
      const float* q = rgp + ((size_t)t * kRGB + c) * 5;
      ws += q[0]; bc += q[1]; in += q[2]; pw += q[3]; gw += q[4];
    }
    sh[t][0] = ce / (double)kNPTS;
    sh[t][1] = 1.0 - (2.0 * pt + 1.0) / (p + tt + 1.0);
    double wss = ws > 1e-6 ? ws : 1e-6;
    sh[t][2] = bc / wss;
    sh[t][3] = 1.0 - (2.0 * in + 1.0) / (pw + gw + 1.0);
  }
  __syncthreads();
  if (t == 0) {
    double a = 0, b = 0, c = 0, d = 0;
    for (int i = 0; i < kB; ++i) { a += sh[i][0]; b += sh[i][1]; c += sh[i][2]; d += sh[i][3]; }
    out[0] = (float)(a / 16.0);
    out[1] = (float)(b / 16.0);
    out[2] = (float)(c / 16.0);
    out[3] = (float)(d / 16.0);
  }
}

extern "C" void kernel_launch(void* const* d_in, const int* in_sizes, int n_in,
                              void* d_out, int out_size, void* d_ws, size_t ws_size,
                              hipStream_t stream) {
  const float* pred = (const float*)d_in[0];
  const float* gt = (const float*)d_in[1];
  const float* coords_os = (const float*)d_in[2];
  const float* coords_rand = (const float*)d_in[3];
  float* out = (float*)d_out;
  char* ws = (char*)d_ws;

  float* pl = (float*)(ws + OFF_PL);
  unsigned char* sel = (unsigned char*)(ws + OFF_SEL);
  int* bbp = (int*)(ws + OFF_BBP);
  float* plp = (float*)(ws + OFF_PLP);
  float* plp2 = (float*)(ws + OFF_PLP2);
  float* rgp = (float*)(ws + OFF_RGP);

  fused1_kernel<<<kSampleBlocks + kBboxBlocks + kRandBlocks, 256, 0, stream>>>(
      pred, gt, coords_os, coords_rand, pl, bbp, plp);
  select_kernel<<<kB, 1024, 0, stream>>>(pl, sel);
  fused3_kernel<<<kB * kPLB + kB * kRGB, 256, 0, stream>>>(
      pred, gt, coords_os, pl, sel, bbp, plp2, rgp);
  finalize_kernel<<<1, 64, 0, stream>>>(plp, plp2, rgp, out);
}